// Round 3
// baseline (168.554 us; speedup 1.0000x reference)
//
#include <hip/hip_runtime.h>
#include <hip/hip_bf16.h>
#include <math.h>

#define DEVI static __device__ __forceinline__

using f32x4  = __attribute__((ext_vector_type(4))) float;
using f32x16 = __attribute__((ext_vector_type(16))) float;
using s16x8  = __attribute__((ext_vector_type(8))) short;
using bf16x8 = __attribute__((ext_vector_type(8))) __bf16;
using i32x4  = __attribute__((ext_vector_type(4))) int;
using u32x2  = __attribute__((ext_vector_type(2))) unsigned int;

constexpr int N   = 8192;
constexpr int KIN = 512;
constexpr int F   = 256;

DEVI unsigned f2bf(float f) {
  unsigned u = __builtin_bit_cast(unsigned, f);
  return ((u + 0x7FFFu + ((u >> 16) & 1u)) >> 16) & 0xFFFFu;
}

DEVI f32x16 mfma32(s16x8 a, s16x8 b, f32x16 c) {
  return __builtin_amdgcn_mfma_f32_32x32x16_bf16(
      __builtin_bit_cast(bf16x8, a), __builtin_bit_cast(bf16x8, b), c, 0, 0, 0);
}

DEVI void gload16(const void* g, void* lds_uniform) {
  __builtin_amdgcn_global_load_lds(
      (const __attribute__((address_space(1))) unsigned*)g,
      (__attribute__((address_space(3))) unsigned*)lds_uniform, 16, 0, 0);
}

// ---------------- cast input f32 -> bf16 (row-major [8192][512]) ----------------
__global__ __launch_bounds__(256) void k_cast(const float* __restrict__ src,
                                              unsigned short* __restrict__ dst,
                                              int n8) {
  int t = blockIdx.x * 256 + threadIdx.x;
  if (t >= n8) return;
  const f32x4* p = (const f32x4*)(src + (size_t)t * 8);
  f32x4 v0 = p[0], v1 = p[1];
  s16x8 o;
  o[0] = (short)f2bf(v0[0]); o[1] = (short)f2bf(v0[1]);
  o[2] = (short)f2bf(v0[2]); o[3] = (short)f2bf(v0[3]);
  o[4] = (short)f2bf(v1[0]); o[5] = (short)f2bf(v1[1]);
  o[6] = (short)f2bf(v1[2]); o[7] = (short)f2bf(v1[3]);
  *(s16x8*)(dst + (size_t)t * 8) = o;
}

// ---------------- W [512][256] f32 -> Wt [256][512] bf16 (transposed) -----------
__global__ __launch_bounds__(256) void k_prep_w(const float* __restrict__ W,
                                                unsigned short* __restrict__ Wt) {
  int t = blockIdx.x * 256 + threadIdx.x;   // 16384 threads
  int c = t >> 6, k0 = (t & 63) * 8;
  s16x8 o;
#pragma unroll
  for (int i = 0; i < 8; ++i) o[i] = (short)f2bf(W[(size_t)(k0 + i) * F + c]);
  *(s16x8*)(Wt + (size_t)c * KIN + k0) = o;
}

// ---------------- h = Xbf @ Wt^T : writes Ht[256][8192] bf16 + E/E5/F/F5 --------
__global__ __launch_bounds__(512) void k_gemm1(const unsigned short* __restrict__ inpb,
                                               const unsigned short* __restrict__ Wt,
                                               const float* __restrict__ a_vec,
                                               unsigned short* __restrict__ Ht,
                                               float* __restrict__ E, float* __restrict__ E5,
                                               float* __restrict__ Fv, float* __restrict__ F5v) {
  __shared__ __align__(16) char lds[4096 + 32768 + 2048];
  char* ldsA = lds;                 // [32 rows][128 B]  (XOR-swizzled)
  char* ldsW = lds + 4096;          // [256 cols][128 B] (XOR-swizzled)
  float* red = (float*)(lds + 36864); // [2][32][8]
  int tid = threadIdx.x, w = tid >> 6, l = tid & 63;
  int r0 = blockIdx.x * 32;
  f32x16 acc;
#pragma unroll
  for (int i = 0; i < 16; ++i) acc[i] = 0.f;

  int lrow8 = l >> 3;
  int koffB = ((l & 7) ^ lrow8) * 8;   // pre-swizzled source k-offset (elements)
  int ra = l & 31, kb = (l >> 5) * 8;
  int colw = w * 32 + ra;

  for (int it = 0; it < 8; ++it) {
    int k0 = it * 64;
    __syncthreads();
    if (w < 4) {
      int row = 8 * w + lrow8;
      gload16(inpb + (size_t)(r0 + row) * KIN + k0 + koffB, ldsA + w * 1024);
    }
#pragma unroll
    for (int qi = 0; qi < 4; ++qi) {
      int q = 4 * w + qi;
      int c = 8 * q + lrow8;
      gload16(Wt + (size_t)c * KIN + k0 + koffB, ldsW + q * 1024);
    }
    __syncthreads();
    s16x8 av[4], bv[4];
#pragma unroll
    for (int kf = 0; kf < 4; ++kf) {
      int kk2 = (kf * 16 + kb) * 2;
      av[kf] = *(const s16x8*)(ldsA + ra * 128 + (kk2 ^ ((ra & 7) << 4)));
      bv[kf] = *(const s16x8*)(ldsW + colw * 128 + (kk2 ^ ((colw & 7) << 4)));
    }
#pragma unroll
    for (int kf = 0; kf < 4; ++kf) acc = mfma32(av[kf], bv[kf], acc);
  }

  float a1 = a_vec[colw], a2 = a_vec[256 + colw];
  int rquad = (l >> 5) * 4;
#pragma unroll
  for (int g = 0; g < 4; ++g) {
    int rowb = g * 8 + rquad;
    unsigned h0 = f2bf(acc[g * 4 + 0]), h1 = f2bf(acc[g * 4 + 1]);
    unsigned h2 = f2bf(acc[g * 4 + 2]), h3 = f2bf(acc[g * 4 + 3]);
    u32x2 pk;
    pk[0] = h0 | (h1 << 16);
    pk[1] = h2 | (h3 << 16);
    *(u32x2*)(Ht + (size_t)colw * N + r0 + rowb) = pk;
  }
#pragma unroll
  for (int g = 0; g < 16; ++g) {
    float vs = acc[g] * a1;
    float vn = acc[g] * a2;
#pragma unroll
    for (int m = 1; m <= 16; m <<= 1) {
      vs += __shfl_xor(vs, m, 64);
      vn += __shfl_xor(vn, m, 64);
    }
    if ((l & 31) == 0) {
      int row = (g & 3) + 8 * (g >> 2) + rquad;
      red[row * 8 + w] = vs;
      red[256 + row * 8 + w] = vn;
    }
  }
  __syncthreads();
  if (tid < 32) {
    float s = 0.f, n2 = 0.f;
#pragma unroll
    for (int i = 0; i < 8; ++i) { s += red[tid * 8 + i]; n2 += red[256 + tid * 8 + i]; }
    E[r0 + tid]   = expf(s);
    E5[r0 + tid]  = expf(0.2f * s);
    Fv[r0 + tid]  = expf(n2);
    F5v[r0 + tid] = expf(0.2f * n2);
  }
}

// ---------------- fused masked-softmax @ h, full row, no split-K ----------------
// grid 256 blocks x 32 rows, 128 j-iters of 64. 512 threads, 8 waves; wave owns
// 32 rows x 32 cols (one f32x16 acc). 4 H buffers (stage depth 3), reg-pf depth 2
// (2 named sets, loop unrolled by 4 for static indexing), 2 P buffers.
// Per-iter VMEM instrs: pf 3 + stage 4. At the wait: in-flight allowed =
// pf(it+2)3 + stage(it+2)4 + pf(it+1)3 + stage(it+1)4 = 14 -> vmcnt(14);
// stage(it) [issued it-3] and pf(it) [it-2] are older and thus retired.
// Epilogue normalizes by the row softmax-denominator and applies ELU directly.
__global__ __launch_bounds__(512) void k_phase2(const int* __restrict__ adj,
                                                const unsigned short* __restrict__ Ht,
                                                const float* __restrict__ E,
                                                const float* __restrict__ E5,
                                                const float* __restrict__ Fv,
                                                const float* __restrict__ F5v,
                                                float* __restrict__ out) {
  __shared__ __align__(16) char lds[131072 + 8192 + 128];
  char* ldsH = lds;                       // 4 x [256 feat][64 j] bf16, swizzled
  char* ldsP = lds + 131072;              // 2 x [32 rows][64 j] bf16, swizzled
  float* ldsS = (float*)(lds + 131072 + 8192); // [32] 1/rowsum

  const int tid = threadIdx.x, w = tid >> 6, l = tid & 63;
  const int r0 = blockIdx.x * 32;

  const int r   = tid >> 4;     // 0..31 P-gen row
  const int cch = tid & 15;     // 4-col chunk within 64
  const float Er = E[r0 + r], E5r = E5[r0 + r];
  float s_part = 0.f;

  const int lrow8 = l >> 3;
  const int koffB = ((l & 7) ^ lrow8) * 8;  // pre-swizzled source offset (elems)
  const int pw_byte = r * 128 + ((cch * 8) ^ ((r & 7) << 4));
  const int ra = l & 31;
  const int kb = (l >> 5) * 8;
  const int colw = w * 32 + (l & 31);
  const size_t adj_row = (size_t)(r0 + r) * (size_t)N;

  f32x16 acc;
#pragma unroll
  for (int i = 0; i < 16; ++i) acc[i] = 0.f;

  // ---- prologue: stage H(0..2) into bufs 0..2; pf regs for it=0 (A), it=1 (B)
#pragma unroll
  for (int b = 0; b < 3; ++b) {
#pragma unroll
    for (int qi = 0; qi < 4; ++qi) {
      int q = 4 * w + qi;
      int c = 8 * q + lrow8;
      gload16(Ht + (size_t)c * N + b * 64 + koffB, ldsH + b * 32768 + q * 1024);
    }
  }
  i32x4 adA = *(const i32x4*)(adj + adj_row + 0 + cch * 4);
  f32x4 fA  = *(const f32x4*)(Fv + 0 + cch * 4);
  f32x4 gA  = *(const f32x4*)(F5v + 0 + cch * 4);
  i32x4 adB = *(const i32x4*)(adj + adj_row + 64 + cch * 4);
  f32x4 fB  = *(const f32x4*)(Fv + 64 + cch * 4);
  f32x4 gB  = *(const f32x4*)(F5v + 64 + cch * 4);

#define P2_BODY(U, ADV, FVV, GVV)                                              \
  {                                                                            \
    const int it  = ito * 4 + (U);                                             \
    const int jpf = ((it + 2) & 127) * 64;                                     \
    const int jst = ((it + 3) & 127) * 64;                                     \
    char* Hc = ldsH + ((U) & 3) * 32768;                                       \
    char* Hs = ldsH + (((U) + 3) & 3) * 32768;                                 \
    char* Pc = ldsP + ((U) & 1) * 4096;                                        \
    /* P-gen(it) from regs pf'd at it-2 (compiler auto-waits; FIFO vmcnt       \
       also retires stage(it) issued at it-3) */                               \
    {                                                                          \
      unsigned hh0, hh1, hh2, hh3;                                             \
      float ss = 0.f;                                                          \
      { float t1 = Er * FVV[0], t2 = E5r * GVV[0];                             \
        float p = (ADV[0] != 0) ? ((t1 >= 1.f) ? t1 : t2) : 0.f;               \
        ss += p; hh0 = f2bf(p); }                                              \
      { float t1 = Er * FVV[1], t2 = E5r * GVV[1];                             \
        float p = (ADV[1] != 0) ? ((t1 >= 1.f) ? t1 : t2) : 0.f;               \
        ss += p; hh1 = f2bf(p); }                                              \
      { float t1 = Er * FVV[2], t2 = E5r * GVV[2];                             \
        float p = (ADV[2] != 0) ? ((t1 >= 1.f) ? t1 : t2) : 0.f;               \
        ss += p; hh2 = f2bf(p); }                                              \
      { float t1 = Er * FVV[3], t2 = E5r * GVV[3];                             \
        float p = (ADV[3] != 0) ? ((t1 >= 1.f) ? t1 : t2) : 0.f;               \
        ss += p; hh3 = f2bf(p); }                                              \
      s_part += ss;                                                            \
      u32x2 pk; pk[0] = hh0 | (hh1 << 16); pk[1] = hh2 | (hh3 << 16);          \
      *(u32x2*)(Pc + pw_byte) = pk;                                            \
    }                                                                          \
    /* refill this reg set for it+2 */                                         \
    ADV = *(const i32x4*)(adj + adj_row + jpf + cch * 4);                      \
    FVV = *(const f32x4*)(Fv + jpf + cch * 4);                                 \
    GVV = *(const f32x4*)(F5v + jpf + cch * 4);                                \
    asm volatile("s_waitcnt vmcnt(14) lgkmcnt(0)" ::: "memory");               \
    __builtin_amdgcn_s_barrier();                                              \
    s16x8 av[4], bv[4];                                                        \
    _Pragma("unroll")                                                          \
    for (int kf = 0; kf < 4; ++kf) {                                           \
      int kk2 = (kf * 16 + kb) * 2;                                            \
      av[kf] = *(const s16x8*)(Pc + ra * 128 + (kk2 ^ ((ra & 7) << 4)));       \
      bv[kf] = *(const s16x8*)(Hc + colw * 128 + (kk2 ^ ((colw & 7) << 4)));   \
    }                                                                          \
    asm volatile("s_waitcnt lgkmcnt(0)" ::: "memory");                         \
    __builtin_amdgcn_sched_barrier(0);                                         \
    /* stage H(it+3): safe post-barrier (all waves done reading this buf) */   \
    _Pragma("unroll")                                                          \
    for (int qi = 0; qi < 4; ++qi) {                                           \
      int q = 4 * w + qi;                                                      \
      int c = 8 * q + lrow8;                                                   \
      gload16(Ht + (size_t)c * N + jst + koffB, Hs + q * 1024);                \
    }                                                                          \
    acc = mfma32(av[0], bv[0], acc);                                           \
    acc = mfma32(av[1], bv[1], acc);                                           \
    acc = mfma32(av[2], bv[2], acc);                                           \
    acc = mfma32(av[3], bv[3], acc);                                           \
  }

  for (int ito = 0; ito < 32; ++ito) {
    P2_BODY(0, adA, fA, gA)
    P2_BODY(1, adB, fB, gB)
    P2_BODY(2, adA, fA, gA)
    P2_BODY(3, adB, fB, gB)
  }
#undef P2_BODY

  // ---- epilogue: rowsum -> 1/s, normalize, ELU, store ----
  __syncthreads();   // drains vmcnt/lgkm (incl. wrapped stages) + barrier
  float s = s_part;
#pragma unroll
  for (int m = 1; m <= 8; m <<= 1) s += __shfl_xor(s, m, 64);
  if ((l & 15) == 0) ldsS[w * 4 + (l >> 4)] = 1.f / s;
  __syncthreads();
#pragma unroll
  for (int g = 0; g < 16; ++g) {
    int row = (g & 3) + 8 * (g >> 2) + (l >> 5) * 4;
    float v = acc[g] * ldsS[row];
    out[(size_t)(r0 + row) * F + colw] = v > 0.f ? v : expm1f(v);
  }
}

extern "C" void kernel_launch(void* const* d_in, const int* in_sizes, int n_in,
                              void* d_out, int out_size, void* d_ws, size_t ws_size,
                              hipStream_t stream) {
  const float* input = (const float*)d_in[0];
  const int*   adj   = (const int*)d_in[1];
  const float* W     = (const float*)d_in[2];
  const float* a     = (const float*)d_in[3];
  float* out = (float*)d_out;
  char* ws = (char*)d_ws;

  unsigned short* inpb = (unsigned short*)(ws);              // 8,388,608 B
  unsigned short* Wt   = (unsigned short*)(ws + 8388608);    //   262,144 B
  unsigned short* Ht   = (unsigned short*)(ws + 8650752);    // 4,194,304 B
  float* E    = (float*)(ws + 12845056);                     //    32,768 B
  float* E5   = (float*)(ws + 12877824);
  float* Fv   = (float*)(ws + 12910592);
  float* F5   = (float*)(ws + 12943360);

  hipLaunchKernelGGL(k_cast,   dim3(2048), dim3(256), 0, stream, input, inpb, 524288);
  hipLaunchKernelGGL(k_prep_w, dim3(64),   dim3(256), 0, stream, W, Wt);
  hipLaunchKernelGGL(k_gemm1,  dim3(256),  dim3(512), 0, stream, inpb, Wt, a, Ht, E, E5, Fv, F5);
  hipLaunchKernelGGL(k_phase2, dim3(256),  dim3(512), 0, stream, adj, Ht, E, E5, Fv, F5, out);
}